// Round 1
// baseline (603.349 us; speedup 1.0000x reference)
//
#include <hip/hip_runtime.h>

#define BB 64
#define SC 640
#define SN 128
#define DD 768
#define CODE_DEF 254
#define NL_DEF 126

// ---------------- K0: per-batch prep -----------------------------------------
// valid lengths (first eos==2), node-row compaction, attn dtype detection.
__global__ __launch_bounds__(64) void k0_prep(
    const int* __restrict__ code_ids, const int* __restrict__ nl_ids,
    const int* __restrict__ pos, const unsigned* __restrict__ attn_u32,
    int* __restrict__ nn, int* __restrict__ node_idx,
    int* __restrict__ len_code, int* __restrict__ len_nl,
    int* __restrict__ flag) {
  int b = blockIdx.x;
  int lane = threadIdx.x;  // 0..63
  int first = CODE_DEF;
  for (int c = 0; c < SC; c += 64) {
    bool is2 = code_ids[b * SC + c + lane] == 2;
    unsigned long long m = __ballot(is2);
    if (m) { first = c + __builtin_ctzll(m); break; }
  }
  int firstn = NL_DEF;
  for (int c = 0; c < SN; c += 64) {
    bool is2 = nl_ids[b * SN + c + lane] == 2;
    unsigned long long m = __ballot(is2);
    if (m) { firstn = c + __builtin_ctzll(m); break; }
  }
  int base = 0;
  for (int c = 0; c < SC; c += 64) {
    bool isn = pos[b * SC + c + lane] == 0;
    unsigned long long m = __ballot(isn);
    int pre = __popcll(m & ((1ull << lane) - 1ull));
    if (isn) node_idx[b * SC + base + pre] = c + lane;
    base += __popcll(m);
  }
  if (lane == 0) { nn[b] = base; len_code[b] = first; len_nl[b] = firstn; }
  if (b == 0) {
    // detect whether attn_mask arrived as uint8 (bool) or int32
    int bad = 0;
    for (int i = lane; i < 1024; i += 64)
      if (attn_u32[i] > 1u) bad = 1;
    unsigned long long m = __ballot(bad);
    if (lane == 0) flag[0] = (m != 0ull) ? 1 : 0;
  }
}

// ---------------- K1: gather code embeddings into code_hidden region ---------
__global__ __launch_bounds__(192) void k1_emb(const int* __restrict__ ids,
                                              const float* __restrict__ Wemb,
                                              float* __restrict__ codeh) {
  long row = blockIdx.x;                 // b*SC + t
  long v = ids[row];
  const float4* s = (const float4*)(Wemb + v * DD);
  float4* d = (float4*)(codeh + row * DD);
  d[threadIdx.x] = s[threadIdx.x];       // 192 threads * float4 = 768 floats
}

// ---------------- K2: masked-mean over token rows for node rows --------------
#define RT 16   // node rows per block
#define TC 128  // t-chunk
__global__ __launch_bounds__(256) void k2_avg(
    const int* __restrict__ attn, const int* __restrict__ pos,
    const int* __restrict__ nn, const int* __restrict__ node_idx,
    const int* __restrict__ flag, float* __restrict__ codeh) {
  int id = blockIdx.x;
  int b = id & 63;       // same-b blocks land on same XCD (stride 64 ≡ 0 mod 8)
  int tile = id >> 6;    // 0..39
  int count = nn[b];
  if (tile * RT >= count) return;
  __shared__ float tokf[SC];
  __shared__ float maskf[RT][TC];
  __shared__ float cnts[RT];
  __shared__ int rowsidx[RT];
  int tid = threadIdx.x;
  for (int i = tid; i < SC; i += 256)
    tokf[i] = (pos[b * SC + i] >= 2) ? 1.f : 0.f;
  if (tid < RT) {
    cnts[tid] = 0.f;
    int g = tile * RT + tid;
    rowsidx[tid] = (g < count) ? node_idx[b * SC + g] : -1;
  }
  __syncthreads();
  float a0[RT], a1[RT], a2[RT];
#pragma unroll
  for (int r = 0; r < RT; ++r) { a0[r] = 0.f; a1[r] = 0.f; a2[r] = 0.f; }
  const int c0 = tid, c1 = tid + 256, c2 = tid + 512;
  const int isu8 = flag[0];
  for (int ci = 0; ci < SC / TC; ++ci) {
    int r = tid >> 4;
    int t0 = (tid & 15) * 8;
    int nrow = rowsidx[r];
    float lc = 0.f;
    if (nrow >= 0) {
      long abase = ((long)b * SC + nrow) * SC + ci * TC + t0;
      if (isu8) {
        const unsigned char* p8 = (const unsigned char*)attn + abase;
#pragma unroll
        for (int j = 0; j < 8; ++j) {
          float f = p8[j] ? tokf[ci * TC + t0 + j] : 0.f;
          maskf[r][t0 + j] = f; lc += f;
        }
      } else {
        const int* p = attn + abase;
#pragma unroll
        for (int j = 0; j < 8; ++j) {
          float f = p[j] ? tokf[ci * TC + t0 + j] : 0.f;
          maskf[r][t0 + j] = f; lc += f;
        }
      }
    } else {
#pragma unroll
      for (int j = 0; j < 8; ++j) maskf[r][t0 + j] = 0.f;
    }
    if (lc != 0.f) atomicAdd(&cnts[r], lc);
    __syncthreads();
    const float* eb = codeh + ((long)b * SC + ci * TC) * DD;
    for (int t = 0; t < TC; ++t) {
      if (tokf[ci * TC + t] == 0.f) continue;  // uniform-branch skip, exact
      float e0 = eb[(long)t * DD + c0];
      float e1 = eb[(long)t * DD + c1];
      float e2 = eb[(long)t * DD + c2];
#pragma unroll
      for (int r2 = 0; r2 < RT; ++r2) {
        float f = maskf[r2][t];
        a0[r2] += f * e0; a1[r2] += f * e1; a2[r2] += f * e2;
      }
    }
    __syncthreads();
  }
#pragma unroll
  for (int r2 = 0; r2 < RT; ++r2) {
    int nrow = rowsidx[r2];
    if (nrow < 0) continue;
    float c = cnts[r2];
    float inv = (c > 0.f) ? 1.f / c : 0.f;
    float* o = codeh + ((long)b * SC + nrow) * DD;
    o[c0] = a0[r2] * inv; o[c1] = a1[r2] * inv; o[c2] = a2[r2] * inv;
  }
}

// ---------------- block reduction helper -------------------------------------
__device__ __forceinline__ float block_sum256(float v, float* sh) {
#pragma unroll
  for (int o = 32; o > 0; o >>= 1) v += __shfl_down(v, o, 64);
  __syncthreads();  // protect sh reuse across calls
  if ((threadIdx.x & 63) == 0) sh[threadIdx.x >> 6] = v;
  __syncthreads();
  return sh[0] + sh[1] + sh[2] + sh[3];
}

// ---------------- K3: l2norm + role + code_probs -----------------------------
__global__ __launch_bounds__(256) void k3_finish(
    float* __restrict__ codeh, const int* __restrict__ roles,
    const float* __restrict__ role_table, const float* __restrict__ w_code,
    const float* __restrict__ b_code, const int* __restrict__ len_code,
    float* __restrict__ code_probs) {
  __shared__ float sh[4];
  long row = blockIdx.x;  // b*SC + s
  int b = (int)(row / SC), s = (int)(row % SC);
  int tid = threadIdx.x;
  int c0 = tid, c1 = tid + 256, c2 = tid + 512;
  float* rp = codeh + row * DD;
  float x0 = rp[c0], x1 = rp[c1], x2 = rp[c2];
  float ss = block_sum256(x0 * x0 + x1 * x1 + x2 * x2, sh);
  float inv = 1.f / fmaxf(sqrtf(ss), 1e-12f);
  float y0 = x0 * inv, y1 = x1 * inv, y2 = x2 * inv;
  rp[c0] = y0; rp[c1] = y1; rp[c2] = y2;
  const float* rt = role_table + (long)roles[row] * DD;
  float dot = (y0 + rt[c0]) * w_code[c0] + (y1 + rt[c1]) * w_code[c1] +
              (y2 + rt[c2]) * w_code[c2];
  dot = block_sum256(dot, sh);
  if (tid == 0) {
    float p = 1.f / (1.f + expf(-(dot + b_code[0])));
    code_probs[row] = (s < len_code[b]) ? p : 0.f;
  }
}

// ---------------- K4: nl branch ----------------------------------------------
__global__ __launch_bounds__(256) void k4_nl(
    const int* __restrict__ ids, const float* __restrict__ Wemb,
    const float* __restrict__ w_nl, const float* __restrict__ b_nl,
    const int* __restrict__ len_nl, float* __restrict__ nlh,
    float* __restrict__ nl_probs) {
  __shared__ float sh[4];
  long row = blockIdx.x;  // b*SN + s
  int b = (int)(row / SN), s = (int)(row % SN);
  int tid = threadIdx.x;
  int c0 = tid, c1 = tid + 256, c2 = tid + 512;
  long v = ids[row];
  const float* src = Wemb + v * DD;
  float x0 = src[c0], x1 = src[c1], x2 = src[c2];
  float ss = block_sum256(x0 * x0 + x1 * x1 + x2 * x2, sh);
  float inv = 1.f / fmaxf(sqrtf(ss), 1e-12f);
  float y0 = x0 * inv, y1 = x1 * inv, y2 = x2 * inv;
  float* o = nlh + row * DD;
  o[c0] = y0; o[c1] = y1; o[c2] = y2;
  float dot = y0 * w_nl[c0] + y1 * w_nl[c1] + y2 * w_nl[c2];
  dot = block_sum256(dot, sh);
  if (tid == 0) {
    float p = 1.f / (1.f + expf(-(dot + b_nl[0])));
    nl_probs[row] = (s < len_nl[b]) ? p : 0.f;
  }
}

// ---------------- K5: sim = nl_hidden · code_hidden^T (tiled SGEMM) ----------
#define KC 32
__global__ __launch_bounds__(256) void k5_sim(const float* __restrict__ nlh,
                                              const float* __restrict__ codeh,
                                              float* __restrict__ sim) {
  __shared__ float As[SN][KC];   // nl rows chunk, XOR-swizzled
  __shared__ float Bs[128][KC];  // code rows chunk, XOR-swizzled
  int id = blockIdx.x;
  int b = id & 63;
  int ct = id >> 6;  // 0..4, column tile of 128
  int tid = threadIdx.x;
  int ty = tid >> 4, tx = tid & 15;
  float c[8][8];
#pragma unroll
  for (int i = 0; i < 8; ++i)
#pragma unroll
    for (int j = 0; j < 8; ++j) c[i][j] = 0.f;
  for (int k0 = 0; k0 < DD; k0 += KC) {
    for (int i = tid; i < (SN * KC) / 4; i += 256) {  // 1024 float4 pairs
      int n = i >> 3;
      int k4 = (i & 7) * 4;
      int sw = (n >> 3) & 7;
      float4 va = *(const float4*)(nlh + ((long)b * SN + n) * DD + k0 + k4);
      As[n][(k4 + 0) ^ sw] = va.x; As[n][(k4 + 1) ^ sw] = va.y;
      As[n][(k4 + 2) ^ sw] = va.z; As[n][(k4 + 3) ^ sw] = va.w;
      float4 vb =
          *(const float4*)(codeh + ((long)b * SC + ct * 128 + n) * DD + k0 + k4);
      Bs[n][(k4 + 0) ^ sw] = vb.x; Bs[n][(k4 + 1) ^ sw] = vb.y;
      Bs[n][(k4 + 2) ^ sw] = vb.z; Bs[n][(k4 + 3) ^ sw] = vb.w;
    }
    __syncthreads();
    int sA = ty & 7, sB = tx & 7;
#pragma unroll
    for (int k = 0; k < KC; ++k) {
      float a[8], bb[8];
      int kA = k ^ sA, kB = k ^ sB;
#pragma unroll
      for (int j = 0; j < 8; ++j) a[j] = As[ty * 8 + j][kA];
#pragma unroll
      for (int j = 0; j < 8; ++j) bb[j] = Bs[tx * 8 + j][kB];
#pragma unroll
      for (int i = 0; i < 8; ++i)
#pragma unroll
        for (int j = 0; j < 8; ++j) c[i][j] += a[i] * bb[j];
    }
    __syncthreads();
  }
  long obase = ((long)b * SN) * SC + (long)ct * 128;
#pragma unroll
  for (int i = 0; i < 8; ++i) {
    int n = ty * 8 + i;
    float* dst = sim + obase + (long)n * SC + tx * 8;
    *(float4*)dst = make_float4(c[i][0], c[i][1], c[i][2], c[i][3]);
    *(float4*)(dst + 4) = make_float4(c[i][4], c[i][5], c[i][6], c[i][7]);
  }
}

// ---------------- launcher ---------------------------------------------------
extern "C" void kernel_launch(void* const* d_in, const int* in_sizes, int n_in,
                              void* d_out, int out_size, void* d_ws,
                              size_t ws_size, hipStream_t stream) {
  const int* code_ids = (const int*)d_in[0];
  const int* attn = (const int*)d_in[1];
  const int* pos = (const int*)d_in[2];
  const int* nl_ids = (const int*)d_in[3];
  const int* roles = (const int*)d_in[4];
  const float* Wemb = (const float*)d_in[5];
  const float* role_table = (const float*)d_in[6];
  const float* w_code = (const float*)d_in[7];
  const float* b_code = (const float*)d_in[8];
  const float* w_nl = (const float*)d_in[9];
  const float* b_nl = (const float*)d_in[10];

  float* out = (float*)d_out;
  float* codeh = out;                      // 64*640*768
  float* code_probs = out + 31457280;      // 64*640
  float* nlh = out + 31498240;             // 64*128*768
  float* nl_probs = out + 37789696;        // 64*128
  float* sim = out + 37797888;             // 64*128*640

  int* wsi = (int*)d_ws;
  int* nn = wsi;                       // 64
  int* node_idx = wsi + 64;            // 64*640
  int* len_code = node_idx + BB * SC;  // 64
  int* len_nl = len_code + 64;         // 64
  int* flag = len_nl + 64;             // 1

  k0_prep<<<BB, 64, 0, stream>>>(code_ids, nl_ids, pos, (const unsigned*)attn,
                                 nn, node_idx, len_code, len_nl, flag);
  k1_emb<<<BB * SC, 192, 0, stream>>>(code_ids, Wemb, codeh);
  k4_nl<<<BB * SN, 256, 0, stream>>>(nl_ids, Wemb, w_nl, b_nl, len_nl, nlh,
                                     nl_probs);
  k2_avg<<<BB * (SC / RT), 256, 0, stream>>>(attn, pos, nn, node_idx, flag,
                                             codeh);
  k3_finish<<<BB * SC, 256, 0, stream>>>(codeh, roles, role_table, w_code,
                                         b_code, len_code, code_probs);
  k5_sim<<<BB * (SC / 128), 256, 0, stream>>>(nlh, codeh, sim);
}

// Round 2
// 338.545 us; speedup vs baseline: 1.7822x; 1.7822x over previous
//
#include <hip/hip_runtime.h>

#define BB 64
#define SC 640
#define SN 128
#define DD 768
#define CODE_DEF 254
#define NL_DEF 126

typedef short bf16x8 __attribute__((ext_vector_type(8)));
typedef float f32x4 __attribute__((ext_vector_type(4)));

__device__ __forceinline__ unsigned short f2bf(float f) {
  unsigned u = __float_as_uint(f);
  u += 0x7fffu + ((u >> 16) & 1u);  // round-to-nearest-even
  return (unsigned short)(u >> 16);
}

// ---------------- K0: per-batch prep -----------------------------------------
__global__ __launch_bounds__(64) void k0_prep(
    const int* __restrict__ code_ids, const int* __restrict__ nl_ids,
    const int* __restrict__ pos, const unsigned* __restrict__ attn_u32,
    int* __restrict__ nn, int* __restrict__ node_idx,
    int* __restrict__ len_code, int* __restrict__ len_nl,
    int* __restrict__ flag) {
  int b = blockIdx.x;
  int lane = threadIdx.x;  // 0..63
  int first = CODE_DEF;
  for (int c = 0; c < SC; c += 64) {
    bool is2 = code_ids[b * SC + c + lane] == 2;
    unsigned long long m = __ballot(is2);
    if (m) { first = c + __builtin_ctzll(m); break; }
  }
  int firstn = NL_DEF;
  for (int c = 0; c < SN; c += 64) {
    bool is2 = nl_ids[b * SN + c + lane] == 2;
    unsigned long long m = __ballot(is2);
    if (m) { firstn = c + __builtin_ctzll(m); break; }
  }
  int base = 0;
  for (int c = 0; c < SC; c += 64) {
    bool isn = pos[b * SC + c + lane] == 0;
    unsigned long long m = __ballot(isn);
    int pre = __popcll(m & ((1ull << lane) - 1ull));
    if (isn) node_idx[b * SC + base + pre] = c + lane;
    base += __popcll(m);
  }
  if (lane == 0) { nn[b] = base; len_code[b] = first; len_nl[b] = firstn; }
  if (b == 0) {
    int bad = 0;
    for (int i = lane; i < 1024; i += 64)
      if (attn_u32[i] > 1u) bad = 1;
    unsigned long long m = __ballot(bad);
    if (lane == 0) flag[0] = (m != 0ull) ? 1 : 0;
  }
}

// ---------------- K1: gather code embeddings into code_hidden region ---------
__global__ __launch_bounds__(192) void k1_emb(const int* __restrict__ ids,
                                              const float* __restrict__ Wemb,
                                              float* __restrict__ codeh) {
  long row = blockIdx.x;
  long v = ids[row];
  const float4* s = (const float4*)(Wemb + v * DD);
  float4* d = (float4*)(codeh + row * DD);
  d[threadIdx.x] = s[threadIdx.x];
}

// ---------------- K2: masked-mean over token rows for node rows --------------
#define RT 16
#define TC 128
__global__ __launch_bounds__(256) void k2_avg(
    const int* __restrict__ attn, const int* __restrict__ pos,
    const int* __restrict__ nn, const int* __restrict__ node_idx,
    const int* __restrict__ flag, float* __restrict__ codeh) {
  int id = blockIdx.x;
  int b = id & 63;
  int tile = id >> 6;
  int count = nn[b];
  if (tile * RT >= count) return;
  __shared__ float tokf[SC];
  __shared__ float maskf[RT][TC];
  __shared__ float cnts[RT];
  __shared__ int rowsidx[RT];
  int tid = threadIdx.x;
  for (int i = tid; i < SC; i += 256)
    tokf[i] = (pos[b * SC + i] >= 2) ? 1.f : 0.f;
  if (tid < RT) {
    cnts[tid] = 0.f;
    int g = tile * RT + tid;
    rowsidx[tid] = (g < count) ? node_idx[b * SC + g] : -1;
  }
  __syncthreads();
  float a0[RT], a1[RT], a2[RT];
#pragma unroll
  for (int r = 0; r < RT; ++r) { a0[r] = 0.f; a1[r] = 0.f; a2[r] = 0.f; }
  const int c0 = tid, c1 = tid + 256, c2 = tid + 512;
  const int isu8 = flag[0];
  for (int ci = 0; ci < SC / TC; ++ci) {
    int r = tid >> 4;
    int t0 = (tid & 15) * 8;
    int nrow = rowsidx[r];
    float lc = 0.f;
    if (nrow >= 0) {
      long abase = ((long)b * SC + nrow) * SC + ci * TC + t0;
      if (isu8) {
        const unsigned char* p8 = (const unsigned char*)attn + abase;
#pragma unroll
        for (int j = 0; j < 8; ++j) {
          float f = p8[j] ? tokf[ci * TC + t0 + j] : 0.f;
          maskf[r][t0 + j] = f; lc += f;
        }
      } else {
        const int* p = attn + abase;
#pragma unroll
        for (int j = 0; j < 8; ++j) {
          float f = p[j] ? tokf[ci * TC + t0 + j] : 0.f;
          maskf[r][t0 + j] = f; lc += f;
        }
      }
    } else {
#pragma unroll
      for (int j = 0; j < 8; ++j) maskf[r][t0 + j] = 0.f;
    }
    if (lc != 0.f) atomicAdd(&cnts[r], lc);
    __syncthreads();
    const float* eb = codeh + ((long)b * SC + ci * TC) * DD;
    for (int t = 0; t < TC; ++t) {
      if (tokf[ci * TC + t] == 0.f) continue;
      float e0 = eb[(long)t * DD + c0];
      float e1 = eb[(long)t * DD + c1];
      float e2 = eb[(long)t * DD + c2];
#pragma unroll
      for (int r2 = 0; r2 < RT; ++r2) {
        float f = maskf[r2][t];
        a0[r2] += f * e0; a1[r2] += f * e1; a2[r2] += f * e2;
      }
    }
    __syncthreads();
  }
#pragma unroll
  for (int r2 = 0; r2 < RT; ++r2) {
    int nrow = rowsidx[r2];
    if (nrow < 0) continue;
    float c = cnts[r2];
    float inv = (c > 0.f) ? 1.f / c : 0.f;
    float* o = codeh + ((long)b * SC + nrow) * DD;
    o[c0] = a0[r2] * inv; o[c1] = a1[r2] * inv; o[c2] = a2[r2] * inv;
  }
}

// ---------------- block reduction helper -------------------------------------
__device__ __forceinline__ float block_sum256(float v, float* sh) {
#pragma unroll
  for (int o = 32; o > 0; o >>= 1) v += __shfl_down(v, o, 64);
  __syncthreads();
  if ((threadIdx.x & 63) == 0) sh[threadIdx.x >> 6] = v;
  __syncthreads();
  return sh[0] + sh[1] + sh[2] + sh[3];
}

// ---------------- K3: l2norm + role + code_probs -----------------------------
__global__ __launch_bounds__(256) void k3_finish(
    float* __restrict__ codeh, const int* __restrict__ roles,
    const float* __restrict__ role_table, const float* __restrict__ w_code,
    const float* __restrict__ b_code, const int* __restrict__ len_code,
    float* __restrict__ code_probs) {
  __shared__ float sh[4];
  long row = blockIdx.x;
  int b = (int)(row / SC), s = (int)(row % SC);
  int tid = threadIdx.x;
  int c0 = tid, c1 = tid + 256, c2 = tid + 512;
  float* rp = codeh + row * DD;
  float x0 = rp[c0], x1 = rp[c1], x2 = rp[c2];
  float ss = block_sum256(x0 * x0 + x1 * x1 + x2 * x2, sh);
  float inv = 1.f / fmaxf(sqrtf(ss), 1e-12f);
  float y0 = x0 * inv, y1 = x1 * inv, y2 = x2 * inv;
  rp[c0] = y0; rp[c1] = y1; rp[c2] = y2;
  const float* rt = role_table + (long)roles[row] * DD;
  float dot = (y0 + rt[c0]) * w_code[c0] + (y1 + rt[c1]) * w_code[c1] +
              (y2 + rt[c2]) * w_code[c2];
  dot = block_sum256(dot, sh);
  if (tid == 0) {
    float p = 1.f / (1.f + expf(-(dot + b_code[0])));
    code_probs[row] = (s < len_code[b]) ? p : 0.f;
  }
}

// ---------------- K4: nl branch ----------------------------------------------
__global__ __launch_bounds__(256) void k4_nl(
    const int* __restrict__ ids, const float* __restrict__ Wemb,
    const float* __restrict__ w_nl, const float* __restrict__ b_nl,
    const int* __restrict__ len_nl, float* __restrict__ nlh,
    float* __restrict__ nl_probs) {
  __shared__ float sh[4];
  long row = blockIdx.x;
  int b = (int)(row / SN), s = (int)(row % SN);
  int tid = threadIdx.x;
  int c0 = tid, c1 = tid + 256, c2 = tid + 512;
  long v = ids[row];
  const float* src = Wemb + v * DD;
  float x0 = src[c0], x1 = src[c1], x2 = src[c2];
  float ss = block_sum256(x0 * x0 + x1 * x1 + x2 * x2, sh);
  float inv = 1.f / fmaxf(sqrtf(ss), 1e-12f);
  float y0 = x0 * inv, y1 = x1 * inv, y2 = x2 * inv;
  float* o = nlh + row * DD;
  o[c0] = y0; o[c1] = y1; o[c2] = y2;
  float dot = y0 * w_nl[c0] + y1 * w_nl[c1] + y2 * w_nl[c2];
  dot = block_sum256(dot, sh);
  if (tid == 0) {
    float p = 1.f / (1.f + expf(-(dot + b_nl[0])));
    nl_probs[row] = (s < len_nl[b]) ? p : 0.f;
  }
}

// ---------------- K5: sim via bf16 MFMA, f32->bf16 convert in-kernel ---------
// tile: 128 (nl rows) x 128 (code rows), K-chunk 64, 4 waves (2x2) of 64x64.
// LDS XOR swizzle: elem k ^= (row&7)<<3  (byte ^= (row&7)<<4), T2 recipe.
__global__ __launch_bounds__(256) void k5_mfma(const float* __restrict__ nlh,
                                               const float* __restrict__ codeh,
                                               float* __restrict__ sim) {
  __shared__ unsigned short As[128 * 64];
  __shared__ unsigned short Bs[128 * 64];
  int id = blockIdx.x;
  int b = id & 63;
  int ct = id >> 6;  // 0..4
  int tid = threadIdx.x;
  int lane = tid & 63;
  int w = tid >> 6;
  int wm = w >> 1, wn = w & 1;

  f32x4 acc[4][4];
#pragma unroll
  for (int m = 0; m < 4; ++m)
#pragma unroll
    for (int n = 0; n < 4; ++n) acc[m][n] = (f32x4){0.f, 0.f, 0.f, 0.f};

  const float* Ag = nlh + (long)b * SN * DD;                  // [128][768]
  const float* Bg = codeh + ((long)b * SC + ct * 128) * DD;   // [128][768]

  for (int c = 0; c < DD / 64; ++c) {
#pragma unroll
    for (int it = 0; it < 8; ++it) {
      int i = tid + 256 * it;  // 0..2047 float4 slots
      int row = i >> 4;        // 0..127
      int k0 = (i & 15) * 4;   // 0..60
      int sk = k0 ^ ((row & 7) << 3);
      float4 va = *(const float4*)(Ag + (long)row * DD + c * 64 + k0);
      ushort4 ua;
      ua.x = f2bf(va.x); ua.y = f2bf(va.y); ua.z = f2bf(va.z); ua.w = f2bf(va.w);
      *(ushort4*)(&As[row * 64 + sk]) = ua;
      float4 vb = *(const float4*)(Bg + (long)row * DD + c * 64 + k0);
      ushort4 ub;
      ub.x = f2bf(vb.x); ub.y = f2bf(vb.y); ub.z = f2bf(vb.z); ub.w = f2bf(vb.w);
      *(ushort4*)(&Bs[row * 64 + sk]) = ub;
    }
    __syncthreads();
#pragma unroll
    for (int ks = 0; ks < 2; ++ks) {
      int kb = ks * 32 + (lane >> 4) * 8;
      bf16x8 af[4], bfr[4];
#pragma unroll
      for (int m = 0; m < 4; ++m) {
        int r = wm * 64 + m * 16 + (lane & 15);
        af[m] = *(const bf16x8*)(&As[r * 64 + (kb ^ ((r & 7) << 3))]);
      }
#pragma unroll
      for (int n = 0; n < 4; ++n) {
        int r = wn * 64 + n * 16 + (lane & 15);
        bfr[n] = *(const bf16x8*)(&Bs[r * 64 + (kb ^ ((r & 7) << 3))]);
      }
#pragma unroll
      for (int m = 0; m < 4; ++m)
#pragma unroll
        for (int n = 0; n < 4; ++n)
          acc[m][n] = __builtin_amdgcn_mfma_f32_16x16x32_bf16(
              af[m], bfr[n], acc[m][n], 0, 0, 0);
    }
    __syncthreads();
  }
  // epilogue: D col = lane&15 (code row), row = (lane>>4)*4 + r (nl row)
  long ob = (long)b * SN * SC + (long)ct * 128;
#pragma unroll
  for (int m = 0; m < 4; ++m) {
    int row0 = wm * 64 + m * 16 + ((lane >> 4) << 2);
#pragma unroll
    for (int n = 0; n < 4; ++n) {
      int col = wn * 64 + n * 16 + (lane & 15);
#pragma unroll
      for (int r = 0; r < 4; ++r)
        sim[ob + (long)(row0 + r) * SC + col] = acc[m][n][r];
    }
  }
}

// ---------------- launcher ---------------------------------------------------
extern "C" void kernel_launch(void* const* d_in, const int* in_sizes, int n_in,
                              void* d_out, int out_size, void* d_ws,
                              size_t ws_size, hipStream_t stream) {
  const int* code_ids = (const int*)d_in[0];
  const int* attn = (const int*)d_in[1];
  const int* pos = (const int*)d_in[2];
  const int* nl_ids = (const int*)d_in[3];
  const int* roles = (const int*)d_in[4];
  const float* Wemb = (const float*)d_in[5];
  const float* role_table = (const float*)d_in[6];
  const float* w_code = (const float*)d_in[7];
  const float* b_code = (const float*)d_in[8];
  const float* w_nl = (const float*)d_in[9];
  const float* b_nl = (const float*)d_in[10];

  float* out = (float*)d_out;
  float* codeh = out;                  // 64*640*768
  float* code_probs = out + 31457280;  // 64*640
  float* nlh = out + 31498240;         // 64*128*768
  float* nl_probs = out + 37789696;    // 64*128
  float* sim = out + 37797888;         // 64*128*640

  int* wsi = (int*)d_ws;
  int* nn = wsi;
  int* node_idx = wsi + 64;
  int* len_code = node_idx + BB * SC;
  int* len_nl = len_code + 64;
  int* flag = len_nl + 64;

  k0_prep<<<BB, 64, 0, stream>>>(code_ids, nl_ids, pos, (const unsigned*)attn,
                                 nn, node_idx, len_code, len_nl, flag);
  k1_emb<<<BB * SC, 192, 0, stream>>>(code_ids, Wemb, codeh);
  k4_nl<<<BB * SN, 256, 0, stream>>>(nl_ids, Wemb, w_nl, b_nl, len_nl, nlh,
                                     nl_probs);
  k2_avg<<<BB * (SC / RT), 256, 0, stream>>>(attn, pos, nn, node_idx, flag,
                                             codeh);
  k3_finish<<<BB * SC, 256, 0, stream>>>(codeh, roles, role_table, w_code,
                                         b_code, len_code, code_probs);
  k5_mfma<<<BB * (SC / 128), 256, 0, stream>>>(nlh, codeh, sim);
}

// Round 3
// 244.995 us; speedup vs baseline: 2.4627x; 1.3818x over previous
//
#include <hip/hip_runtime.h>

#define BB 64
#define SC 640
#define SN 128
#define DD 768
#define CODE_DEF 254
#define NL_DEF 126

typedef short bf16x8 __attribute__((ext_vector_type(8)));
typedef float f32x4 __attribute__((ext_vector_type(4)));

__device__ __forceinline__ unsigned short f2bf(float f) {
  unsigned u = __float_as_uint(f);
  u += 0x7fffu + ((u >> 16) & 1u);  // round-to-nearest-even
  return (unsigned short)(u >> 16);
}

// ---------------- K0: per-batch prep -----------------------------------------
__global__ __launch_bounds__(64) void k0_prep(
    const int* __restrict__ code_ids, const int* __restrict__ nl_ids,
    const int* __restrict__ pos, const unsigned* __restrict__ attn_u32,
    int* __restrict__ nn, int* __restrict__ node_idx,
    int* __restrict__ len_code, int* __restrict__ len_nl,
    int* __restrict__ flag) {
  int b = blockIdx.x;
  int lane = threadIdx.x;  // 0..63
  int first = CODE_DEF;
  for (int c = 0; c < SC; c += 64) {
    bool is2 = code_ids[b * SC + c + lane] == 2;
    unsigned long long m = __ballot(is2);
    if (m) { first = c + __builtin_ctzll(m); break; }
  }
  int firstn = NL_DEF;
  for (int c = 0; c < SN; c += 64) {
    bool is2 = nl_ids[b * SN + c + lane] == 2;
    unsigned long long m = __ballot(is2);
    if (m) { firstn = c + __builtin_ctzll(m); break; }
  }
  int base = 0;
  for (int c = 0; c < SC; c += 64) {
    bool isn = pos[b * SC + c + lane] == 0;
    unsigned long long m = __ballot(isn);
    int pre = __popcll(m & ((1ull << lane) - 1ull));
    if (isn) node_idx[b * SC + base + pre] = c + lane;
    base += __popcll(m);
  }
  if (lane == 0) { nn[b] = base; len_code[b] = first; len_nl[b] = firstn; }
  if (b == 0) {
    int bad = 0;
    for (int i = lane; i < 1024; i += 64)
      if (attn_u32[i] > 1u) bad = 1;
    unsigned long long m = __ballot(bad);
    if (lane == 0) flag[0] = (m != 0ull) ? 1 : 0;
  }
}

// ---------------- K1: gather code embeddings into code_hidden region ---------
__global__ __launch_bounds__(192) void k1_emb(const int* __restrict__ ids,
                                              const float* __restrict__ Wemb,
                                              float* __restrict__ codeh) {
  long row = blockIdx.x;
  long v = ids[row];
  const float4* s = (const float4*)(Wemb + v * DD);
  float4* d = (float4*)(codeh + row * DD);
  d[threadIdx.x] = s[threadIdx.x];
}

// ---------------- K2: node-avg as bf16 MFMA GEMM ------------------------------
// avg[node, d] = sum_t mask[node,t] * emb[t,d] / cnt[node]
// tile M=128 nodes x N=256 d, K-chunk 64; 4 waves 2x2 (64x128 each).
// As: mask [128][64] bf16, XOR swz (elem k ^= (row&7)<<3).
// Bs: embT [256][64] bf16, same swz on t. Staged via in-register 4x4 transpose.
__global__ __launch_bounds__(256) void k2_mfma(
    const int* __restrict__ attn, const int* __restrict__ pos,
    const int* __restrict__ nn, const int* __restrict__ node_idx,
    const int* __restrict__ flag, float* __restrict__ codeh) {
  __shared__ unsigned short As[128 * 64];
  __shared__ unsigned short Bs[256 * 64];
  __shared__ unsigned short tokbf[SC];
  __shared__ float cnts[128];
  __shared__ int rowsidx[128];

  int id = blockIdx.x;
  int b = id & 63;          // same-b blocks -> same XCD (stride 64)
  int rest = id >> 6;       // 0..14
  int ntile = rest % 5;
  int dtile = rest / 5;     // 0..2
  int count = nn[b];
  if (ntile * 128 >= count) return;

  int tid = threadIdx.x;
  for (int i = tid; i < SC; i += 256)
    tokbf[i] = (pos[b * SC + i] >= 2) ? (unsigned short)0x3F80 : (unsigned short)0;
  if (tid < 128) {
    cnts[tid] = 0.f;
    int g = ntile * 128 + tid;
    rowsidx[tid] = (g < count) ? node_idx[b * SC + g] : -1;
  }
  __syncthreads();

  const int isu8 = flag[0];
  int lane = tid & 63;
  int w = tid >> 6, wm = w >> 1, wn = w & 1;

  f32x4 acc[4][8];
#pragma unroll
  for (int m = 0; m < 4; ++m)
#pragma unroll
    for (int n = 0; n < 8; ++n) acc[m][n] = (f32x4){0.f, 0.f, 0.f, 0.f};

  const float* Eg = codeh + (long)b * SC * DD + dtile * 256;
  const int r = tid >> 1, h = tid & 1;  // mask staging: row, half
  const int nrow = rowsidx[r];
  const int sw = (r & 7) << 3;

  for (int c = 0; c < SC / 64; ++c) {
    // ---- mask staging: 128 rows x 64 t; thread: row r, t in [h*32, h*32+32)
    int ic = 0;
#pragma unroll
    for (int g = 0; g < 4; ++g) {
      int tl = h * 32 + g * 8;        // local t of 8-group
      int tg = c * 64 + tl;           // global t
      unsigned short mv[8];
      if (nrow >= 0) {
        if (isu8) {
          const unsigned char* p8 =
              (const unsigned char*)attn + ((long)b * SC + nrow) * SC + tg;
          uint2 q = *(const uint2*)p8;
#pragma unroll
          for (int j = 0; j < 4; ++j) {
            mv[j] = ((q.x >> (8 * j)) & 0xffu) ? tokbf[tg + j] : 0;
            mv[4 + j] = ((q.y >> (8 * j)) & 0xffu) ? tokbf[tg + 4 + j] : 0;
          }
        } else {
          const int* p = attn + ((long)b * SC + nrow) * SC + tg;
          int4 q0 = *(const int4*)p;
          int4 q1 = *(const int4*)(p + 4);
          mv[0] = q0.x ? tokbf[tg + 0] : 0; mv[1] = q0.y ? tokbf[tg + 1] : 0;
          mv[2] = q0.z ? tokbf[tg + 2] : 0; mv[3] = q0.w ? tokbf[tg + 3] : 0;
          mv[4] = q1.x ? tokbf[tg + 4] : 0; mv[5] = q1.y ? tokbf[tg + 5] : 0;
          mv[6] = q1.z ? tokbf[tg + 6] : 0; mv[7] = q1.w ? tokbf[tg + 7] : 0;
        }
#pragma unroll
        for (int j = 0; j < 8; ++j) ic += (mv[j] != 0);
      } else {
#pragma unroll
        for (int j = 0; j < 8; ++j) mv[j] = 0;
      }
      int sk = tl ^ sw;  // 8-aligned group stays contiguous under XOR
      ushort4 u0 = {mv[0], mv[1], mv[2], mv[3]};
      ushort4 u1 = {mv[4], mv[5], mv[6], mv[7]};
      *(ushort4*)(&As[r * 64 + sk]) = u0;
      *(ushort4*)(&As[r * 64 + sk + 4]) = u1;
    }
    if (ic) atomicAdd(&cnts[r], (float)ic);

    // ---- emb staging with in-register 4x4 transpose -> Bs[d][t]
#pragma unroll
    for (int q = 0; q < 4; ++q) {
      int task = tid + 256 * q;   // 1024 tasks: 16 t-groups x 64 d-groups
      int tg4 = task >> 6;        // t-group 0..15
      int d0 = (task & 63) * 4;   // d 0..255
      f32x4 va[4];
#pragma unroll
      for (int j = 0; j < 4; ++j)
        va[j] = *(const f32x4*)(Eg + (long)(c * 64 + tg4 * 4 + j) * DD + d0);
#pragma unroll
      for (int dj = 0; dj < 4; ++dj) {
        int d = d0 + dj;
        ushort4 u = {f2bf(va[0][dj]), f2bf(va[1][dj]), f2bf(va[2][dj]),
                     f2bf(va[3][dj])};
        *(ushort4*)(&Bs[d * 64 + ((tg4 * 4) ^ ((d & 7) << 3))]) = u;
      }
    }
    __syncthreads();

    // ---- MFMA phase
#pragma unroll
    for (int ks = 0; ks < 2; ++ks) {
      int kb = ks * 32 + (lane >> 4) * 8;
      bf16x8 af[4], bf[8];
#pragma unroll
      for (int m = 0; m < 4; ++m) {
        int rr = wm * 64 + m * 16 + (lane & 15);
        af[m] = *(const bf16x8*)(&As[rr * 64 + (kb ^ ((rr & 7) << 3))]);
      }
#pragma unroll
      for (int n = 0; n < 8; ++n) {
        int cc = wn * 128 + n * 16 + (lane & 15);
        bf[n] = *(const bf16x8*)(&Bs[cc * 64 + (kb ^ ((cc & 7) << 3))]);
      }
#pragma unroll
      for (int m = 0; m < 4; ++m)
#pragma unroll
        for (int n = 0; n < 8; ++n)
          acc[m][n] = __builtin_amdgcn_mfma_f32_16x16x32_bf16(af[m], bf[n],
                                                              acc[m][n], 0, 0, 0);
    }
    __syncthreads();
  }

  // ---- epilogue: divide by count, scatter to node rows
#pragma unroll
  for (int m = 0; m < 4; ++m) {
    int row0 = wm * 64 + m * 16 + ((lane >> 4) << 2);
#pragma unroll
    for (int rr = 0; rr < 4; ++rr) {
      int row = row0 + rr;
      int nr = rowsidx[row];
      if (nr < 0) continue;
      float cnt = cnts[row];
      float inv = (cnt > 0.f) ? 1.f / cnt : 0.f;
      float* orow = codeh + ((long)b * SC + nr) * DD + dtile * 256 + wn * 128;
#pragma unroll
      for (int n = 0; n < 8; ++n)
        orow[n * 16 + (lane & 15)] = acc[m][n][rr] * inv;
    }
  }
}

// ---------------- block reduction helper -------------------------------------
__device__ __forceinline__ float block_sum256(float v, float* sh) {
#pragma unroll
  for (int o = 32; o > 0; o >>= 1) v += __shfl_down(v, o, 64);
  __syncthreads();
  if ((threadIdx.x & 63) == 0) sh[threadIdx.x >> 6] = v;
  __syncthreads();
  return sh[0] + sh[1] + sh[2] + sh[3];
}

// ---------------- K3: l2norm + role + code_probs -----------------------------
__global__ __launch_bounds__(256) void k3_finish(
    float* __restrict__ codeh, const int* __restrict__ roles,
    const float* __restrict__ role_table, const float* __restrict__ w_code,
    const float* __restrict__ b_code, const int* __restrict__ len_code,
    float* __restrict__ code_probs) {
  __shared__ float sh[4];
  long row = blockIdx.x;
  int b = (int)(row / SC), s = (int)(row % SC);
  int tid = threadIdx.x;
  int c0 = tid, c1 = tid + 256, c2 = tid + 512;
  float* rp = codeh + row * DD;
  float x0 = rp[c0], x1 = rp[c1], x2 = rp[c2];
  float ss = block_sum256(x0 * x0 + x1 * x1 + x2 * x2, sh);
  float inv = 1.f / fmaxf(sqrtf(ss), 1e-12f);
  float y0 = x0 * inv, y1 = x1 * inv, y2 = x2 * inv;
  rp[c0] = y0; rp[c1] = y1; rp[c2] = y2;
  const float* rt = role_table + (long)roles[row] * DD;
  float dot = (y0 + rt[c0]) * w_code[c0] + (y1 + rt[c1]) * w_code[c1] +
              (y2 + rt[c2]) * w_code[c2];
  dot = block_sum256(dot, sh);
  if (tid == 0) {
    float p = 1.f / (1.f + expf(-(dot + b_code[0])));
    code_probs[row] = (s < len_code[b]) ? p : 0.f;
  }
}

// ---------------- K4: nl branch ----------------------------------------------
__global__ __launch_bounds__(256) void k4_nl(
    const int* __restrict__ ids, const float* __restrict__ Wemb,
    const float* __restrict__ w_nl, const float* __restrict__ b_nl,
    const int* __restrict__ len_nl, float* __restrict__ nlh,
    float* __restrict__ nl_probs) {
  __shared__ float sh[4];
  long row = blockIdx.x;
  int b = (int)(row / SN), s = (int)(row % SN);
  int tid = threadIdx.x;
  int c0 = tid, c1 = tid + 256, c2 = tid + 512;
  long v = ids[row];
  const float* src = Wemb + v * DD;
  float x0 = src[c0], x1 = src[c1], x2 = src[c2];
  float ss = block_sum256(x0 * x0 + x1 * x1 + x2 * x2, sh);
  float inv = 1.f / fmaxf(sqrtf(ss), 1e-12f);
  float y0 = x0 * inv, y1 = x1 * inv, y2 = x2 * inv;
  float* o = nlh + row * DD;
  o[c0] = y0; o[c1] = y1; o[c2] = y2;
  float dot = y0 * w_nl[c0] + y1 * w_nl[c1] + y2 * w_nl[c2];
  dot = block_sum256(dot, sh);
  if (tid == 0) {
    float p = 1.f / (1.f + expf(-(dot + b_nl[0])));
    nl_probs[row] = (s < len_nl[b]) ? p : 0.f;
  }
}

// ---------------- K5: sim via bf16 MFMA --------------------------------------
__global__ __launch_bounds__(256) void k5_mfma(const float* __restrict__ nlh,
                                               const float* __restrict__ codeh,
                                               float* __restrict__ sim) {
  __shared__ unsigned short As[128 * 64];
  __shared__ unsigned short Bs[128 * 64];
  int id = blockIdx.x;
  int b = id & 63;
  int ct = id >> 6;  // 0..4
  int tid = threadIdx.x;
  int lane = tid & 63;
  int w = tid >> 6;
  int wm = w >> 1, wn = w & 1;

  f32x4 acc[4][4];
#pragma unroll
  for (int m = 0; m < 4; ++m)
#pragma unroll
    for (int n = 0; n < 4; ++n) acc[m][n] = (f32x4){0.f, 0.f, 0.f, 0.f};

  const float* Ag = nlh + (long)b * SN * DD;
  const float* Bg = codeh + ((long)b * SC + ct * 128) * DD;

  for (int c = 0; c < DD / 64; ++c) {
#pragma unroll
    for (int it = 0; it < 8; ++it) {
      int i = tid + 256 * it;
      int row = i >> 4;
      int k0 = (i & 15) * 4;
      int sk = k0 ^ ((row & 7) << 3);
      float4 va = *(const float4*)(Ag + (long)row * DD + c * 64 + k0);
      ushort4 ua;
      ua.x = f2bf(va.x); ua.y = f2bf(va.y); ua.z = f2bf(va.z); ua.w = f2bf(va.w);
      *(ushort4*)(&As[row * 64 + sk]) = ua;
      float4 vb = *(const float4*)(Bg + (long)row * DD + c * 64 + k0);
      ushort4 ub;
      ub.x = f2bf(vb.x); ub.y = f2bf(vb.y); ub.z = f2bf(vb.z); ub.w = f2bf(vb.w);
      *(ushort4*)(&Bs[row * 64 + sk]) = ub;
    }
    __syncthreads();
#pragma unroll
    for (int ks = 0; ks < 2; ++ks) {
      int kb = ks * 32 + (lane >> 4) * 8;
      bf16x8 af[4], bfr[4];
#pragma unroll
      for (int m = 0; m < 4; ++m) {
        int rr = wm * 64 + m * 16 + (lane & 15);
        af[m] = *(const bf16x8*)(&As[rr * 64 + (kb ^ ((rr & 7) << 3))]);
      }
#pragma unroll
      for (int n = 0; n < 4; ++n) {
        int rr = wn * 64 + n * 16 + (lane & 15);
        bfr[n] = *(const bf16x8*)(&Bs[rr * 64 + (kb ^ ((rr & 7) << 3))]);
      }
#pragma unroll
      for (int m = 0; m < 4; ++m)
#pragma unroll
        for (int n = 0; n < 4; ++n)
          acc[m][n] = __builtin_amdgcn_mfma_f32_16x16x32_bf16(
              af[m], bfr[n], acc[m][n], 0, 0, 0);
    }
    __syncthreads();
  }
  long ob = (long)b * SN * SC + (long)ct * 128;
#pragma unroll
  for (int m = 0; m < 4; ++m) {
    int row0 = wm * 64 + m * 16 + ((lane >> 4) << 2);
#pragma unroll
    for (int n = 0; n < 4; ++n) {
      int col = wn * 64 + n * 16 + (lane & 15);
#pragma unroll
      for (int rr = 0; rr < 4; ++rr)
        sim[ob + (long)(row0 + rr) * SC + col] = acc[m][n][rr];
    }
  }
}

// ---------------- launcher ---------------------------------------------------
extern "C" void kernel_launch(void* const* d_in, const int* in_sizes, int n_in,
                              void* d_out, int out_size, void* d_ws,
                              size_t ws_size, hipStream_t stream) {
  const int* code_ids = (const int*)d_in[0];
  const int* attn = (const int*)d_in[1];
  const int* pos = (const int*)d_in[2];
  const int* nl_ids = (const int*)d_in[3];
  const int* roles = (const int*)d_in[4];
  const float* Wemb = (const float*)d_in[5];
  const float* role_table = (const float*)d_in[6];
  const float* w_code = (const float*)d_in[7];
  const float* b_code = (const float*)d_in[8];
  const float* w_nl = (const float*)d_in[9];
  const float* b_nl = (const float*)d_in[10];

  float* out = (float*)d_out;
  float* codeh = out;                  // 64*640*768
  float* code_probs = out + 31457280;  // 64*640
  float* nlh = out + 31498240;         // 64*128*768
  float* nl_probs = out + 37789696;    // 64*128
  float* sim = out + 37797888;         // 64*128*640

  int* wsi = (int*)d_ws;
  int* nn = wsi;
  int* node_idx = wsi + 64;
  int* len_code = node_idx + BB * SC;
  int* len_nl = len_code + 64;
  int* flag = len_nl + 64;

  k0_prep<<<BB, 64, 0, stream>>>(code_ids, nl_ids, pos, (const unsigned*)attn,
                                 nn, node_idx, len_code, len_nl, flag);
  k1_emb<<<BB * SC, 192, 0, stream>>>(code_ids, Wemb, codeh);
  k4_nl<<<BB * SN, 256, 0, stream>>>(nl_ids, Wemb, w_nl, b_nl, len_nl, nlh,
                                     nl_probs);
  k2_mfma<<<BB * 15, 256, 0, stream>>>(attn, pos, nn, node_idx, flag, codeh);
  k3_finish<<<BB * SC, 256, 0, stream>>>(codeh, roles, role_table, w_code,
                                         b_code, len_code, code_probs);
  k5_mfma<<<BB * (SC / 128), 256, 0, stream>>>(nlh, codeh, sim);
}

// Round 4
// 217.169 us; speedup vs baseline: 2.7782x; 1.1281x over previous
//
#include <hip/hip_runtime.h>

#define BB 64
#define SC 640
#define SN 128
#define DD 768
#define CODE_DEF 254
#define NL_DEF 126

typedef short bf16x8 __attribute__((ext_vector_type(8)));
typedef float f32x4 __attribute__((ext_vector_type(4)));

__device__ __forceinline__ unsigned short f2bf(float f) {
  unsigned u = __float_as_uint(f);
  u += 0x7fffu + ((u >> 16) & 1u);  // round-to-nearest-even
  return (unsigned short)(u >> 16);
}

// ---------------- K0: per-batch prep -----------------------------------------
__global__ __launch_bounds__(64) void k0_prep(
    const int* __restrict__ code_ids, const int* __restrict__ nl_ids,
    const int* __restrict__ pos, const unsigned* __restrict__ attn_u32,
    int* __restrict__ nn, int* __restrict__ node_idx,
    int* __restrict__ len_code, int* __restrict__ len_nl,
    int* __restrict__ flag) {
  int b = blockIdx.x;
  int lane = threadIdx.x;  // 0..63
  int first = CODE_DEF;
  for (int c = 0; c < SC; c += 64) {
    bool is2 = code_ids[b * SC + c + lane] == 2;
    unsigned long long m = __ballot(is2);
    if (m) { first = c + __builtin_ctzll(m); break; }
  }
  int firstn = NL_DEF;
  for (int c = 0; c < SN; c += 64) {
    bool is2 = nl_ids[b * SN + c + lane] == 2;
    unsigned long long m = __ballot(is2);
    if (m) { firstn = c + __builtin_ctzll(m); break; }
  }
  int base = 0;
  for (int c = 0; c < SC; c += 64) {
    bool isn = pos[b * SC + c + lane] == 0;
    unsigned long long m = __ballot(isn);
    int pre = __popcll(m & ((1ull << lane) - 1ull));
    if (isn) node_idx[b * SC + base + pre] = c + lane;
    base += __popcll(m);
  }
  if (lane == 0) { nn[b] = base; len_code[b] = first; len_nl[b] = firstn; }
  if (b == 0) {
    int bad = 0;
    for (int i = lane; i < 1024; i += 64)
      if (attn_u32[i] > 1u) bad = 1;
    unsigned long long m = __ballot(bad);
    if (lane == 0) flag[0] = (m != 0ull) ? 1 : 0;
  }
}

// ---------------- K0b: pack (attn && token_mask) bits per node row -----------
// mbits64[b][slot][k] covers t = k*64..k*64+63; counts[b][slot] = popcount.
// slot in 0..255; slots >= nn[b] are zeroed.
__global__ __launch_bounds__(256) void k0b_mask(
    const int* __restrict__ attn, const int* __restrict__ pos,
    const int* __restrict__ nn, const int* __restrict__ node_idx,
    const int* __restrict__ flag,
    unsigned long long* __restrict__ mbits64, float* __restrict__ counts) {
  int id = blockIdx.x;
  int b = id & 63, g = id >> 6;  // g 0..15
  int w = threadIdx.x >> 6, lane = threadIdx.x & 63;
  int count = nn[b];
  int isu8 = flag[0];
  for (int rr = 0; rr < 4; ++rr) {
    int slot = g * 16 + w * 4 + rr;
    long obase = ((long)b * 256 + slot) * 10;
    if (slot >= count) {
      if (lane < 10) mbits64[obase + lane] = 0ull;
      if (lane == 0) counts[b * 256 + slot] = 0.f;
      continue;
    }
    int nrow = node_idx[b * SC + slot];
    int tot = 0;
    for (int k = 0; k < 10; ++k) {
      int t = k * 64 + lane;
      bool tk = pos[b * SC + t] >= 2;
      bool av;
      if (isu8)
        av = ((const unsigned char*)attn)[((long)b * SC + nrow) * SC + t] != 0;
      else
        av = attn[((long)b * SC + nrow) * SC + t] != 0;
      unsigned long long m = __ballot(av && tk);
      if (lane == 0) mbits64[obase + k] = m;
      tot += __popcll(m);
    }
    if (lane == 0) counts[b * 256 + slot] = (float)tot;
  }
}

// ---------------- K1: gather code embeddings into code_hidden region ---------
__global__ __launch_bounds__(192) void k1_emb(const int* __restrict__ ids,
                                              const float* __restrict__ Wemb,
                                              float* __restrict__ codeh) {
  long row = blockIdx.x;
  long v = ids[row];
  const float4* s = (const float4*)(Wemb + v * DD);
  float4* d = (float4*)(codeh + row * DD);
  d[threadIdx.x] = s[threadIdx.x];
}

// ---------------- K2: node-avg GEMM, 128 nodes x 128 d, dbuf LDS -------------
// As: mask bf16 [128 node][64 t], swz elem^=(row&7)<<3 (k5-proven).
// Bs: embT bf16 [128 d][64 t], swz elem^=(((d>>2)&7)^((d&3)<<1))<<3
//     (2-way/free on frag reads, ~4-way on transpose writes).
__global__ __launch_bounds__(256) void k2_mfma(
    const unsigned* __restrict__ mbits, const float* __restrict__ counts,
    const int* __restrict__ nn, const int* __restrict__ node_idx,
    float* __restrict__ codeh) {
  __shared__ unsigned short As[2][128 * 64];
  __shared__ unsigned short Bs[2][128 * 64];
  __shared__ int rowsidx[128];
  int id = blockIdx.x;
  int b = id & 63;       // same-b -> same XCD (stride 64)
  int g = id >> 6;       // 0..11
  int ntile = g / 6, dtile = g % 6;
  int count = nn[b];
  if (ntile * 128 >= count) return;
  int tid = threadIdx.x;
  if (tid < 128) {
    int slot = ntile * 128 + tid;
    rowsidx[tid] = (slot < count) ? node_idx[b * SC + slot] : -1;
  }
  const int lane = tid & 63, w = tid >> 6, wm = w >> 1, wn = w & 1;

  f32x4 acc[4][4];
#pragma unroll
  for (int m = 0; m < 4; ++m)
#pragma unroll
    for (int n = 0; n < 4; ++n) acc[m][n] = (f32x4){0.f, 0.f, 0.f, 0.f};

  const float* Eg = codeh + (long)b * SC * DD + dtile * 128;
  const int r_ = tid >> 1, h_ = tid & 1;
  const unsigned* mrow = mbits + ((long)b * 256 + ntile * 128 + r_) * 20;
  int tg4[2], d0[2];
#pragma unroll
  for (int q = 0; q < 2; ++q) {
    int task = tid + 256 * q;
    tg4[q] = task >> 5;       // 0..15
    d0[q] = (task & 31) * 4;  // 0..124
  }

  f32x4 va[2][4];
  unsigned bitsv;

#define LOADC(cc)                                                         \
  {                                                                       \
    bitsv = mrow[(cc) * 2 + h_];                                          \
    _Pragma("unroll") for (int q = 0; q < 2; ++q)                         \
        _Pragma("unroll") for (int j = 0; j < 4; ++j) va[q][j] =          \
        *(const f32x4*)(Eg + (long)((cc) * 64 + tg4[q] * 4 + j) * DD +    \
                        d0[q]);                                           \
  }

#define WRITEB(bf_)                                                       \
  {                                                                       \
    unsigned short* Ab = As[bf_];                                         \
    unsigned short* Bb = Bs[bf_];                                         \
    _Pragma("unroll") for (int gg = 0; gg < 4; ++gg) {                    \
      int tl = h_ * 32 + gg * 8;                                          \
      bf16x8 u;                                                           \
      _Pragma("unroll") for (int j = 0; j < 8; ++j) u[j] =                \
          ((bitsv >> (gg * 8 + j)) & 1u) ? (short)0x3F80 : (short)0;      \
      *(bf16x8*)(&Ab[r_ * 64 + (tl ^ ((r_ & 7) << 3))]) = u;              \
    }                                                                     \
    _Pragma("unroll") for (int q = 0; q < 2; ++q)                         \
        _Pragma("unroll") for (int dj = 0; dj < 4; ++dj) {                \
      int d = d0[q] + dj;                                                 \
      ushort4 u = {f2bf(va[q][0][dj]), f2bf(va[q][1][dj]),                \
                   f2bf(va[q][2][dj]), f2bf(va[q][3][dj])};               \
      int s = ((((d >> 2) & 7) ^ ((d & 3) << 1)) << 3);                   \
      *(ushort4*)(&Bb[d * 64 + ((tg4[q] * 4) ^ s)]) = u;                  \
    }                                                                     \
  }

#define MFMAP(bf_)                                                        \
  {                                                                       \
    const unsigned short* Ab = As[bf_];                                   \
    const unsigned short* Bb = Bs[bf_];                                   \
    _Pragma("unroll") for (int ks = 0; ks < 2; ++ks) {                    \
      int kb = ks * 32 + (lane >> 4) * 8;                                 \
      bf16x8 af[4], bfv[4];                                               \
      _Pragma("unroll") for (int m = 0; m < 4; ++m) {                     \
        int rr = wm * 64 + m * 16 + (lane & 15);                          \
        af[m] = *(const bf16x8*)(&Ab[rr * 64 + (kb ^ ((rr & 7) << 3))]);  \
      }                                                                   \
      _Pragma("unroll") for (int n = 0; n < 4; ++n) {                     \
        int cc = wn * 64 + n * 16 + (lane & 15);                          \
        int s = ((((cc >> 2) & 7) ^ ((cc & 3) << 1)) << 3);               \
        bfv[n] = *(const bf16x8*)(&Bb[cc * 64 + (kb ^ s)]);               \
      }                                                                   \
      _Pragma("unroll") for (int m = 0; m < 4; ++m)                       \
          _Pragma("unroll") for (int n = 0; n < 4; ++n) acc[m][n] =       \
          __builtin_amdgcn_mfma_f32_16x16x32_bf16(af[m], bfv[n],          \
                                                  acc[m][n], 0, 0, 0);    \
    }                                                                     \
  }

  LOADC(0);
  WRITEB(0);
  __syncthreads();
  for (int c = 0; c < 10; ++c) {
    if (c < 9) LOADC(c + 1);
    MFMAP(c & 1);
    if (c < 9) WRITEB((c + 1) & 1);
    __syncthreads();
  }

  // epilogue: divide by count, scatter to node rows
  float* outb = codeh + (long)b * SC * DD + dtile * 128 + wn * 64;
#pragma unroll
  for (int m = 0; m < 4; ++m) {
    int row0 = wm * 64 + m * 16 + ((lane >> 4) << 2);
#pragma unroll
    for (int rr2 = 0; rr2 < 4; ++rr2) {
      int slotr = row0 + rr2;
      int nr = rowsidx[slotr];
      if (nr < 0) continue;
      float cnt = counts[b * 256 + ntile * 128 + slotr];
      float inv = (cnt > 0.f) ? 1.f / cnt : 0.f;
      float* orow = outb + (long)nr * DD;
#pragma unroll
      for (int n = 0; n < 4; ++n)
        orow[n * 16 + (lane & 15)] = acc[m][n][rr2] * inv;
    }
  }
#undef LOADC
#undef WRITEB
#undef MFMAP
}

// ---------------- block reduction helper -------------------------------------
__device__ __forceinline__ float block_sum256(float v, float* sh) {
#pragma unroll
  for (int o = 32; o > 0; o >>= 1) v += __shfl_down(v, o, 64);
  __syncthreads();
  if ((threadIdx.x & 63) == 0) sh[threadIdx.x >> 6] = v;
  __syncthreads();
  return sh[0] + sh[1] + sh[2] + sh[3];
}

// ---------------- K3: l2norm + role + code_probs -----------------------------
__global__ __launch_bounds__(256) void k3_finish(
    float* __restrict__ codeh, const int* __restrict__ roles,
    const float* __restrict__ role_table, const float* __restrict__ w_code,
    const float* __restrict__ b_code, const int* __restrict__ len_code,
    float* __restrict__ code_probs) {
  __shared__ float sh[4];
  long row = blockIdx.x;
  int b = (int)(row / SC), s = (int)(row % SC);
  int tid = threadIdx.x;
  int c0 = tid, c1 = tid + 256, c2 = tid + 512;
  float* rp = codeh + row * DD;
  float x0 = rp[c0], x1 = rp[c1], x2 = rp[c2];
  float ss = block_sum256(x0 * x0 + x1 * x1 + x2 * x2, sh);
  float inv = 1.f / fmaxf(sqrtf(ss), 1e-12f);
  float y0 = x0 * inv, y1 = x1 * inv, y2 = x2 * inv;
  rp[c0] = y0; rp[c1] = y1; rp[c2] = y2;
  const float* rt = role_table + (long)roles[row] * DD;
  float dot = (y0 + rt[c0]) * w_code[c0] + (y1 + rt[c1]) * w_code[c1] +
              (y2 + rt[c2]) * w_code[c2];
  dot = block_sum256(dot, sh);
  if (tid == 0) {
    float p = 1.f / (1.f + expf(-(dot + b_code[0])));
    code_probs[row] = (s < len_code[b]) ? p : 0.f;
  }
}

// ---------------- K4: nl branch ----------------------------------------------
__global__ __launch_bounds__(256) void k4_nl(
    const int* __restrict__ ids, const float* __restrict__ Wemb,
    const float* __restrict__ w_nl, const float* __restrict__ b_nl,
    const int* __restrict__ len_nl, float* __restrict__ nlh,
    float* __restrict__ nl_probs) {
  __shared__ float sh[4];
  long row = blockIdx.x;
  int b = (int)(row / SN), s = (int)(row % SN);
  int tid = threadIdx.x;
  int c0 = tid, c1 = tid + 256, c2 = tid + 512;
  long v = ids[row];
  const float* src = Wemb + v * DD;
  float x0 = src[c0], x1 = src[c1], x2 = src[c2];
  float ss = block_sum256(x0 * x0 + x1 * x1 + x2 * x2, sh);
  float inv = 1.f / fmaxf(sqrtf(ss), 1e-12f);
  float y0 = x0 * inv, y1 = x1 * inv, y2 = x2 * inv;
  float* o = nlh + row * DD;
  o[c0] = y0; o[c1] = y1; o[c2] = y2;
  float dot = y0 * w_nl[c0] + y1 * w_nl[c1] + y2 * w_nl[c2];
  dot = block_sum256(dot, sh);
  if (tid == 0) {
    float p = 1.f / (1.f + expf(-(dot + b_nl[0])));
    nl_probs[row] = (s < len_nl[b]) ? p : 0.f;
  }
}

// ---------------- K5: sim via bf16 MFMA --------------------------------------
__global__ __launch_bounds__(256) void k5_mfma(const float* __restrict__ nlh,
                                               const float* __restrict__ codeh,
                                               float* __restrict__ sim) {
  __shared__ unsigned short As[128 * 64];
  __shared__ unsigned short Bs[128 * 64];
  int id = blockIdx.x;
  int b = id & 63;
  int ct = id >> 6;  // 0..4
  int tid = threadIdx.x;
  int lane = tid & 63;
  int w = tid >> 6;
  int wm = w >> 1, wn = w & 1;

  f32x4 acc[4][4];
#pragma unroll
  for (int m = 0; m < 4; ++m)
#pragma unroll
    for (int n = 0; n < 4; ++n) acc[m][n] = (f32x4){0.f, 0.f, 0.f, 0.f};

  const float* Ag = nlh + (long)b * SN * DD;
  const float* Bg = codeh + ((long)b * SC + ct * 128) * DD;

  for (int c = 0; c < DD / 64; ++c) {
#pragma unroll
    for (int it = 0; it < 8; ++it) {
      int i = tid + 256 * it;
      int row = i >> 4;
      int k0 = (i & 15) * 4;
      int sk = k0 ^ ((row & 7) << 3);
      float4 vaa = *(const float4*)(Ag + (long)row * DD + c * 64 + k0);
      ushort4 ua;
      ua.x = f2bf(vaa.x); ua.y = f2bf(vaa.y); ua.z = f2bf(vaa.z); ua.w = f2bf(vaa.w);
      *(ushort4*)(&As[row * 64 + sk]) = ua;
      float4 vbb = *(const float4*)(Bg + (long)row * DD + c * 64 + k0);
      ushort4 ub;
      ub.x = f2bf(vbb.x); ub.y = f2bf(vbb.y); ub.z = f2bf(vbb.z); ub.w = f2bf(vbb.w);
      *(ushort4*)(&Bs[row * 64 + sk]) = ub;
    }
    __syncthreads();
#pragma unroll
    for (int ks = 0; ks < 2; ++ks) {
      int kb = ks * 32 + (lane >> 4) * 8;
      bf16x8 af[4], bfr[4];
#pragma unroll
      for (int m = 0; m < 4; ++m) {
        int rr = wm * 64 + m * 16 + (lane & 15);
        af[m] = *(const bf16x8*)(&As[rr * 64 + (kb ^ ((rr & 7) << 3))]);
      }
#pragma unroll
      for (int n = 0; n < 4; ++n) {
        int rr = wn * 64 + n * 16 + (lane & 15);
        bfr[n] = *(const bf16x8*)(&Bs[rr * 64 + (kb ^ ((rr & 7) << 3))]);
      }
#pragma unroll
      for (int m = 0; m < 4; ++m)
#pragma unroll
        for (int n = 0; n < 4; ++n)
          acc[m][n] = __builtin_amdgcn_mfma_f32_16x16x32_bf16(
              af[m], bfr[n], acc[m][n], 0, 0, 0);
    }
    __syncthreads();
  }
  long ob = (long)b * SN * SC + (long)ct * 128;
#pragma unroll
  for (int m = 0; m < 4; ++m) {
    int row0 = wm * 64 + m * 16 + ((lane >> 4) << 2);
#pragma unroll
    for (int n = 0; n < 4; ++n) {
      int col = wn * 64 + n * 16 + (lane & 15);
#pragma unroll
      for (int rr = 0; rr < 4; ++rr)
        sim[ob + (long)(row0 + rr) * SC + col] = acc[m][n][rr];
    }
  }
}

// ---------------- launcher ---------------------------------------------------
extern "C" void kernel_launch(void* const* d_in, const int* in_sizes, int n_in,
                              void* d_out, int out_size, void* d_ws,
                              size_t ws_size, hipStream_t stream) {
  const int* code_ids = (const int*)d_in[0];
  const int* attn = (const int*)d_in[1];
  const int* pos = (const int*)d_in[2];
  const int* nl_ids = (const int*)d_in[3];
  const int* roles = (const int*)d_in[4];
  const float* Wemb = (const float*)d_in[5];
  const float* role_table = (const float*)d_in[6];
  const float* w_code = (const float*)d_in[7];
  const float* b_code = (const float*)d_in[8];
  const float* w_nl = (const float*)d_in[9];
  const float* b_nl = (const float*)d_in[10];

  float* out = (float*)d_out;
  float* codeh = out;                  // 64*640*768
  float* code_probs = out + 31457280;  // 64*640
  float* nlh = out + 31498240;         // 64*128*768
  float* nl_probs = out + 37789696;    // 64*128
  float* sim = out + 37797888;         // 64*128*640

  int* wsi = (int*)d_ws;
  int* nn = wsi;                        // 64
  int* node_idx = wsi + 64;             // 64*640
  int* len_code = node_idx + BB * SC;   // 64
  int* len_nl = len_code + 64;          // 64
  int* flag = len_nl + 64;              // 1
  unsigned* mbits = (unsigned*)(wsi + 49152);          // 64*256*20 u32
  float* counts = (float*)(wsi + 49152 + 327680);      // 64*256

  k0_prep<<<BB, 64, 0, stream>>>(code_ids, nl_ids, pos, (const unsigned*)attn,
                                 nn, node_idx, len_code, len_nl, flag);
  k0b_mask<<<BB * 16, 256, 0, stream>>>(attn, pos, nn, node_idx, flag,
                                        (unsigned long long*)mbits, counts);
  k1_emb<<<BB * SC, 192, 0, stream>>>(code_ids, Wemb, codeh);
  k4_nl<<<BB * SN, 256, 0, stream>>>(nl_ids, Wemb, w_nl, b_nl, len_nl, nlh,
                                     nl_probs);
  k2_mfma<<<BB * 12, 256, 0, stream>>>(mbits, counts, nn, node_idx, codeh);
  k3_finish<<<BB * SC, 256, 0, stream>>>(codeh, roles, role_table, w_code,
                                         b_code, len_code, code_probs);
  k5_mfma<<<BB * (SC / 128), 256, 0, stream>>>(nlh, codeh, sim);
}

// Round 5
// 174.805 us; speedup vs baseline: 3.4516x; 1.2423x over previous
//
#include <hip/hip_runtime.h>

#define BB 64
#define SC 640
#define SN 128
#define DD 768
#define CODE_DEF 254
#define NL_DEF 126

typedef short bf16x8 __attribute__((ext_vector_type(8)));
typedef float f32x4 __attribute__((ext_vector_type(4)));

__device__ __forceinline__ unsigned short f2bf(float f) {
  unsigned u = __float_as_uint(f);
  u += 0x7fffu + ((u >> 16) & 1u);  // round-to-nearest-even
  return (unsigned short)(u >> 16);
}

// ---------------- K0: per-batch prep -----------------------------------------
__global__ __launch_bounds__(64) void k0_prep(
    const int* __restrict__ code_ids, const int* __restrict__ nl_ids,
    const int* __restrict__ pos, const unsigned* __restrict__ attn_u32,
    int* __restrict__ nn, int* __restrict__ node_idx,
    int* __restrict__ len_code, int* __restrict__ len_nl,
    int* __restrict__ flag) {
  int b = blockIdx.x;
  int lane = threadIdx.x;  // 0..63
  int first = CODE_DEF;
  for (int c = 0; c < SC; c += 64) {
    bool is2 = code_ids[b * SC + c + lane] == 2;
    unsigned long long m = __ballot(is2);
    if (m) { first = c + __builtin_ctzll(m); break; }
  }
  int firstn = NL_DEF;
  for (int c = 0; c < SN; c += 64) {
    bool is2 = nl_ids[b * SN + c + lane] == 2;
    unsigned long long m = __ballot(is2);
    if (m) { firstn = c + __builtin_ctzll(m); break; }
  }
  int base = 0;
  for (int c = 0; c < SC; c += 64) {
    bool isn = pos[b * SC + c + lane] == 0;
    unsigned long long m = __ballot(isn);
    int pre = __popcll(m & ((1ull << lane) - 1ull));
    if (isn) node_idx[b * SC + base + pre] = c + lane;
    base += __popcll(m);
  }
  if (lane == 0) { nn[b] = base; len_code[b] = first; len_nl[b] = firstn; }
  if (b == 0) {
    int bad = 0;
    for (int i = lane; i < 1024; i += 64)
      if (attn_u32[i] > 1u) bad = 1;
    unsigned long long m = __ballot(bad);
    if (lane == 0) flag[0] = (m != 0ull) ? 1 : 0;
  }
}

// ---------------- K0b: pack (attn && token_mask) bits per node row -----------
__global__ __launch_bounds__(256) void k0b_mask(
    const int* __restrict__ attn, const int* __restrict__ pos,
    const int* __restrict__ nn, const int* __restrict__ node_idx,
    const int* __restrict__ flag,
    unsigned long long* __restrict__ mbits64, float* __restrict__ counts) {
  int id = blockIdx.x;
  int b = id & 63, g = id >> 6;  // g 0..15
  int w = threadIdx.x >> 6, lane = threadIdx.x & 63;
  int count = nn[b];
  int isu8 = flag[0];
  for (int rr = 0; rr < 4; ++rr) {
    int slot = g * 16 + w * 4 + rr;
    long obase = ((long)b * 256 + slot) * 10;
    if (slot >= count) {
      if (lane < 10) mbits64[obase + lane] = 0ull;
      if (lane == 0) counts[b * 256 + slot] = 0.f;
      continue;
    }
    int nrow = node_idx[b * SC + slot];
    int tot = 0;
    for (int k = 0; k < 10; ++k) {
      int t = k * 64 + lane;
      bool tk = pos[b * SC + t] >= 2;
      bool av;
      if (isu8)
        av = ((const unsigned char*)attn)[((long)b * SC + nrow) * SC + t] != 0;
      else
        av = attn[((long)b * SC + nrow) * SC + t] != 0;
      unsigned long long m = __ballot(av && tk);
      if (lane == 0) mbits64[obase + k] = m;
      tot += __popcll(m);
    }
    if (lane == 0) counts[b * 256 + slot] = (float)tot;
  }
}

// ---------------- K2: node-avg GEMM, B gathered directly from Wemb -----------
// As: mask bf16 [128 node][64 t], swz elem^=(row&7)<<3.
// Bs: embT bf16 [128 d][64 t], swz elem^=(((d>>2)&7)^((d&3)<<1))<<3.
// Writes RAW avg (mean) into node rows of codeh; k3 normalizes later.
__global__ __launch_bounds__(256) void k2_mfma(
    const unsigned* __restrict__ mbits, const float* __restrict__ counts,
    const int* __restrict__ nn, const int* __restrict__ node_idx,
    const int* __restrict__ code_ids, const float* __restrict__ Wemb,
    float* __restrict__ codeh) {
  __shared__ unsigned short As[2][128 * 64];
  __shared__ unsigned short Bs[2][128 * 64];
  __shared__ int rowsidx[128];
  __shared__ int cid[SC];
  int id = blockIdx.x;
  int b = id & 63;       // same-b -> same XCD (stride 64)
  int g = id >> 6;       // 0..11
  int ntile = g / 6, dtile = g % 6;
  int count = nn[b];
  if (ntile * 128 >= count) return;
  int tid = threadIdx.x;
  for (int i = tid; i < SC; i += 256) cid[i] = code_ids[b * SC + i];
  if (tid < 128) {
    int slot = ntile * 128 + tid;
    rowsidx[tid] = (slot < count) ? node_idx[b * SC + slot] : -1;
  }
  __syncthreads();
  const int lane = tid & 63, w = tid >> 6, wm = w >> 1, wn = w & 1;
  const int dcol = dtile * 128;

  f32x4 acc[4][4];
#pragma unroll
  for (int m = 0; m < 4; ++m)
#pragma unroll
    for (int n = 0; n < 4; ++n) acc[m][n] = (f32x4){0.f, 0.f, 0.f, 0.f};

  const int r_ = tid >> 1, h_ = tid & 1;
  const unsigned* mrow = mbits + ((long)b * 256 + ntile * 128 + r_) * 20;
  int tg4[2], d0[2];
#pragma unroll
  for (int q = 0; q < 2; ++q) {
    int task = tid + 256 * q;
    tg4[q] = task >> 5;       // 0..15
    d0[q] = (task & 31) * 4;  // 0..124
  }

  f32x4 va[2][4];
  unsigned bitsv;

#define LOADC(cc)                                                         \
  {                                                                       \
    bitsv = mrow[(cc) * 2 + h_];                                          \
    _Pragma("unroll") for (int q = 0; q < 2; ++q)                         \
        _Pragma("unroll") for (int j = 0; j < 4; ++j) va[q][j] =          \
        *(const f32x4*)(Wemb +                                            \
                        (long)cid[(cc) * 64 + tg4[q] * 4 + j] * DD +      \
                        dcol + d0[q]);                                    \
  }

#define WRITEB(bf_)                                                       \
  {                                                                       \
    unsigned short* Ab = As[bf_];                                         \
    unsigned short* Bb = Bs[bf_];                                         \
    _Pragma("unroll") for (int gg = 0; gg < 4; ++gg) {                    \
      int tl = h_ * 32 + gg * 8;                                          \
      bf16x8 u;                                                           \
      _Pragma("unroll") for (int j = 0; j < 8; ++j) u[j] =                \
          ((bitsv >> (gg * 8 + j)) & 1u) ? (short)0x3F80 : (short)0;      \
      *(bf16x8*)(&Ab[r_ * 64 + (tl ^ ((r_ & 7) << 3))]) = u;              \
    }                                                                     \
    _Pragma("unroll") for (int q = 0; q < 2; ++q)                         \
        _Pragma("unroll") for (int dj = 0; dj < 4; ++dj) {                \
      int d = d0[q] + dj;                                                 \
      ushort4 u = {f2bf(va[q][0][dj]), f2bf(va[q][1][dj]),                \
                   f2bf(va[q][2][dj]), f2bf(va[q][3][dj])};               \
      int s = ((((d >> 2) & 7) ^ ((d & 3) << 1)) << 3);                   \
      *(ushort4*)(&Bb[d * 64 + ((tg4[q] * 4) ^ s)]) = u;                  \
    }                                                                     \
  }

#define MFMAP(bf_)                                                        \
  {                                                                       \
    const unsigned short* Ab = As[bf_];                                   \
    const unsigned short* Bb = Bs[bf_];                                   \
    _Pragma("unroll") for (int ks = 0; ks < 2; ++ks) {                    \
      int kb = ks * 32 + (lane >> 4) * 8;                                 \
      bf16x8 af[4], bfv[4];                                               \
      _Pragma("unroll") for (int m = 0; m < 4; ++m) {                     \
        int rr = wm * 64 + m * 16 + (lane & 15);                          \
        af[m] = *(const bf16x8*)(&Ab[rr * 64 + (kb ^ ((rr & 7) << 3))]);  \
      }                                                                   \
      _Pragma("unroll") for (int n = 0; n < 4; ++n) {                     \
        int cc = wn * 64 + n * 16 + (lane & 15);                          \
        int s = ((((cc >> 2) & 7) ^ ((cc & 3) << 1)) << 3);               \
        bfv[n] = *(const bf16x8*)(&Bb[cc * 64 + (kb ^ s)]);               \
      }                                                                   \
      _Pragma("unroll") for (int m = 0; m < 4; ++m)                       \
          _Pragma("unroll") for (int n = 0; n < 4; ++n) acc[m][n] =       \
          __builtin_amdgcn_mfma_f32_16x16x32_bf16(af[m], bfv[n],          \
                                                  acc[m][n], 0, 0, 0);    \
    }                                                                     \
  }

  LOADC(0);
  WRITEB(0);
  __syncthreads();
  for (int c = 0; c < 10; ++c) {
    if (c < 9) LOADC(c + 1);
    MFMAP(c & 1);
    if (c < 9) WRITEB((c + 1) & 1);
    __syncthreads();
  }

  // epilogue: divide by count, scatter raw avg to node rows
  float* outb = codeh + (long)b * SC * DD + dcol + wn * 64;
#pragma unroll
  for (int m = 0; m < 4; ++m) {
    int row0 = wm * 64 + m * 16 + ((lane >> 4) << 2);
#pragma unroll
    for (int rr2 = 0; rr2 < 4; ++rr2) {
      int slotr = row0 + rr2;
      int nr = rowsidx[slotr];
      if (nr < 0) continue;
      float cnt = counts[b * 256 + ntile * 128 + slotr];
      float inv = (cnt > 0.f) ? 1.f / cnt : 0.f;
      float* orow = outb + (long)nr * DD;
#pragma unroll
      for (int n = 0; n < 4; ++n)
        orow[n * 16 + (lane & 15)] = acc[m][n][rr2] * inv;
    }
  }
#undef LOADC
#undef WRITEB
#undef MFMAP
}

// ---------------- K3: fused gather + l2norm + role + probs (wave/row) --------
__global__ __launch_bounds__(256) void k3_fused(
    const int* __restrict__ code_ids, const int* __restrict__ pos,
    const float* __restrict__ Wemb, float* __restrict__ codeh,
    const int* __restrict__ roles, const float* __restrict__ role_table,
    const float* __restrict__ w_code, const float* __restrict__ b_code,
    const int* __restrict__ len_code, float* __restrict__ code_probs) {
  int w = threadIdx.x >> 6, lane = threadIdx.x & 63;
  long row = (long)blockIdx.x * 4 + w;
  int b = (int)(row / SC), s = (int)(row % SC);
  float* rp = codeh + row * DD;
  const float* src =
      (pos[row] == 0) ? rp : (Wemb + (long)code_ids[row] * DD);
  f32x4 x[3];
#pragma unroll
  for (int j = 0; j < 3; ++j)
    x[j] = *(const f32x4*)(src + lane * 4 + j * 256);
  float ss = 0.f;
#pragma unroll
  for (int j = 0; j < 3; ++j)
#pragma unroll
    for (int e = 0; e < 4; ++e) ss += x[j][e] * x[j][e];
#pragma unroll
  for (int o = 32; o > 0; o >>= 1) ss += __shfl_xor(ss, o, 64);
  float inv = 1.f / fmaxf(sqrtf(ss), 1e-12f);
  const float* rt = role_table + (long)roles[row] * DD;
  float dot = 0.f;
#pragma unroll
  for (int j = 0; j < 3; ++j) {
    f32x4 r = *(const f32x4*)(rt + lane * 4 + j * 256);
    f32x4 wc = *(const f32x4*)(w_code + lane * 4 + j * 256);
    f32x4 y;
#pragma unroll
    for (int e = 0; e < 4; ++e) {
      y[e] = x[j][e] * inv;
      dot += (y[e] + r[e]) * wc[e];
    }
    *(f32x4*)(rp + lane * 4 + j * 256) = y;
  }
#pragma unroll
  for (int o = 32; o > 0; o >>= 1) dot += __shfl_xor(dot, o, 64);
  if (lane == 0) {
    float p = 1.f / (1.f + expf(-(dot + b_code[0])));
    code_probs[row] = (s < len_code[b]) ? p : 0.f;
  }
}

// ---------------- K4: nl branch (wave/row) ------------------------------------
__global__ __launch_bounds__(256) void k4_nl(
    const int* __restrict__ ids, const float* __restrict__ Wemb,
    const float* __restrict__ w_nl, const float* __restrict__ b_nl,
    const int* __restrict__ len_nl, float* __restrict__ nlh,
    float* __restrict__ nl_probs) {
  int w = threadIdx.x >> 6, lane = threadIdx.x & 63;
  long row = (long)blockIdx.x * 4 + w;
  int b = (int)(row / SN), s = (int)(row % SN);
  const float* src = Wemb + (long)ids[row] * DD;
  f32x4 x[3];
#pragma unroll
  for (int j = 0; j < 3; ++j)
    x[j] = *(const f32x4*)(src + lane * 4 + j * 256);
  float ss = 0.f;
#pragma unroll
  for (int j = 0; j < 3; ++j)
#pragma unroll
    for (int e = 0; e < 4; ++e) ss += x[j][e] * x[j][e];
#pragma unroll
  for (int o = 32; o > 0; o >>= 1) ss += __shfl_xor(ss, o, 64);
  float inv = 1.f / fmaxf(sqrtf(ss), 1e-12f);
  float* o = nlh + row * DD;
  float dot = 0.f;
#pragma unroll
  for (int j = 0; j < 3; ++j) {
    f32x4 wn = *(const f32x4*)(w_nl + lane * 4 + j * 256);
    f32x4 y;
#pragma unroll
    for (int e = 0; e < 4; ++e) {
      y[e] = x[j][e] * inv;
      dot += y[e] * wn[e];
    }
    *(f32x4*)(o + lane * 4 + j * 256) = y;
  }
#pragma unroll
  for (int of = 32; of > 0; of >>= 1) dot += __shfl_xor(dot, of, 64);
  if (lane == 0) {
    float p = 1.f / (1.f + expf(-(dot + b_nl[0])));
    nl_probs[row] = (s < len_nl[b]) ? p : 0.f;
  }
}

// ---------------- K5: sim via bf16 MFMA --------------------------------------
__global__ __launch_bounds__(256) void k5_mfma(const float* __restrict__ nlh,
                                               const float* __restrict__ codeh,
                                               float* __restrict__ sim) {
  __shared__ unsigned short As[128 * 64];
  __shared__ unsigned short Bs[128 * 64];
  int id = blockIdx.x;
  int b = id & 63;
  int ct = id >> 6;  // 0..4
  int tid = threadIdx.x;
  int lane = tid & 63;
  int w = tid >> 6;
  int wm = w >> 1, wn = w & 1;

  f32x4 acc[4][4];
#pragma unroll
  for (int m = 0; m < 4; ++m)
#pragma unroll
    for (int n = 0; n < 4; ++n) acc[m][n] = (f32x4){0.f, 0.f, 0.f, 0.f};

  const float* Ag = nlh + (long)b * SN * DD;
  const float* Bg = codeh + ((long)b * SC + ct * 128) * DD;

  for (int c = 0; c < DD / 64; ++c) {
#pragma unroll
    for (int it = 0; it < 8; ++it) {
      int i = tid + 256 * it;
      int row = i >> 4;
      int k0 = (i & 15) * 4;
      int sk = k0 ^ ((row & 7) << 3);
      float4 vaa = *(const float4*)(Ag + (long)row * DD + c * 64 + k0);
      ushort4 ua;
      ua.x = f2bf(vaa.x); ua.y = f2bf(vaa.y); ua.z = f2bf(vaa.z); ua.w = f2bf(vaa.w);
      *(ushort4*)(&As[row * 64 + sk]) = ua;
      float4 vbb = *(const float4*)(Bg + (long)row * DD + c * 64 + k0);
      ushort4 ub;
      ub.x = f2bf(vbb.x); ub.y = f2bf(vbb.y); ub.z = f2bf(vbb.z); ub.w = f2bf(vbb.w);
      *(ushort4*)(&Bs[row * 64 + sk]) = ub;
    }
    __syncthreads();
#pragma unroll
    for (int ks = 0; ks < 2; ++ks) {
      int kb = ks * 32 + (lane >> 4) * 8;
      bf16x8 af[4], bfr[4];
#pragma unroll
      for (int m = 0; m < 4; ++m) {
        int rr = wm * 64 + m * 16 + (lane & 15);
        af[m] = *(const bf16x8*)(&As[rr * 64 + (kb ^ ((rr & 7) << 3))]);
      }
#pragma unroll
      for (int n = 0; n < 4; ++n) {
        int rr = wn * 64 + n * 16 + (lane & 15);
        bfr[n] = *(const bf16x8*)(&Bs[rr * 64 + (kb ^ ((rr & 7) << 3))]);
      }
#pragma unroll
      for (int m = 0; m < 4; ++m)
#pragma unroll
        for (int n = 0; n < 4; ++n)
          acc[m][n] = __builtin_amdgcn_mfma_f32_16x16x32_bf16(
              af[m], bfr[n], acc[m][n], 0, 0, 0);
    }
    __syncthreads();
  }
  long ob = (long)b * SN * SC + (long)ct * 128;
#pragma unroll
  for (int m = 0; m < 4; ++m) {
    int row0 = wm * 64 + m * 16 + ((lane >> 4) << 2);
#pragma unroll
    for (int n = 0; n < 4; ++n) {
      int col = wn * 64 + n * 16 + (lane & 15);
#pragma unroll
      for (int rr = 0; rr < 4; ++rr)
        sim[ob + (long)(row0 + rr) * SC + col] = acc[m][n][rr];
    }
  }
}

// ---------------- launcher ---------------------------------------------------
extern "C" void kernel_launch(void* const* d_in, const int* in_sizes, int n_in,
                              void* d_out, int out_size, void* d_ws,
                              size_t ws_size, hipStream_t stream) {
  const int* code_ids = (const int*)d_in[0];
  const int* attn = (const int*)d_in[1];
  const int* pos = (const int*)d_in[2];
  const int* nl_ids = (const int*)d_in[3];
  const int* roles = (const int*)d_in[4];
  const float* Wemb = (const float*)d_in[5];
  const float* role_table = (const float*)d_in[6];
  const float* w_code = (const float*)d_in[7];
  const float* b_code = (const float*)d_in[8];
  const float* w_nl = (const float*)d_in[9];
  const float* b_nl = (const float*)d_in[10];

  float* out = (float*)d_out;
  float* codeh = out;                  // 64*640*768
  float* code_probs = out + 31457280;  // 64*640
  float* nlh = out + 31498240;         // 64*128*768
  float* nl_probs = out + 37789696;    // 64*128
  float* sim = out + 37797888;         // 64*128*640

  int* wsi = (int*)d_ws;
  int* nn = wsi;                        // 64
  int* node_idx = wsi + 64;             // 64*640
  int* len_code = node_idx + BB * SC;   // 64
  int* len_nl = len_code + 64;          // 64
  int* flag = len_nl + 64;              // 1
  unsigned* mbits = (unsigned*)(wsi + 49152);          // 64*256*20 u32
  float* counts = (float*)(wsi + 49152 + 327680);      // 64*256

  k0_prep<<<BB, 64, 0, stream>>>(code_ids, nl_ids, pos, (const unsigned*)attn,
                                 nn, node_idx, len_code, len_nl, flag);
  k0b_mask<<<BB * 16, 256, 0, stream>>>(attn, pos, nn, node_idx, flag,
                                        (unsigned long long*)mbits, counts);
  k4_nl<<<BB * SN / 4, 256, 0, stream>>>(nl_ids, Wemb, w_nl, b_nl, len_nl, nlh,
                                         nl_probs);
  k2_mfma<<<BB * 12, 256, 0, stream>>>(mbits, counts, nn, node_idx, code_ids,
                                       Wemb, codeh);
  k3_fused<<<BB * SC / 4, 256, 0, stream>>>(code_ids, pos, Wemb, codeh, roles,
                                            role_table, w_code, b_code,
                                            len_code, code_probs);
  k5_mfma<<<BB * (SC / 128), 256, 0, stream>>>(nlh, codeh, sim);
}